// Round 5
// baseline (1054.834 us; speedup 1.0000x reference)
//
#include <hip/hip_runtime.h>
#include <hip/hip_bf16.h>
#include <math.h>

#define D      256
#define H      8
#define HD     32
#define TOPK   10
#define CAP    500000
#define BATCH  256

#define G1     512            // phase-1 blocks (2 per CU — LDS 49.6KB fits twice)
#define T1     512            // phase-1 threads (8 waves)
#define NT     32             // hologram rows per round
#define ROUNDS 31             // 15 unrolled pairs + 1 tail round
#define CHUNK  (NT*ROUNDS)    // 992 rows per block (512*992 = 507904 >= CAP)
#define TOPB   16             // per-block per-row candidates (also per-half-list size)
#define MSEL   32             // exactly-rescored candidates per row

typedef float  f32x16 __attribute__((ext_vector_type(16)));
typedef __bf16 bf16x8 __attribute__((ext_vector_type(8)));

union FragCvt { uint4 u; bf16x8 v; };

__device__ __forceinline__ unsigned bfpair(float lo, float hi){
  unsigned a = __builtin_bit_cast(unsigned, lo);
  unsigned b = __builtin_bit_cast(unsigned, hi);
  a += 0x7FFFu + ((a >> 16) & 1u);   // RNE to bf16
  b += 0x7FFFu + ((b >> 16) & 1u);
  return (a >> 16) | (b & 0xFFFF0000u);
}
__device__ __forceinline__ uint4 pack8(float4 p0, float4 p1){
  uint4 u;
  u.x = bfpair(p0.x, p0.y); u.y = bfpair(p0.z, p0.w);
  u.z = bfpair(p1.x, p1.y); u.w = bfpair(p1.z, p1.w);
  return u;
}

// register-resident top-16 list: replace current-min slot, rescan min (all static idx)
__device__ __forceinline__ void list_insert(float (&tv)[TOPB], int (&ti)[TOPB],
                                            float &minv, int &mins, float v, int gi){
  #pragma unroll
  for (int q = 0; q < TOPB; ++q){ if (q == mins){ tv[q] = v; ti[q] = gi; } }
  float mv = tv[0]; int ms = 0;
  #pragma unroll
  for (int q = 1; q < TOPB; ++q){
    float x = tv[q];
    if (x < mv){ mv = x; ms = q; }
  }
  minv = mv; mins = ms;
}

// one pipelined round (selection fully in registers; sims never touch LDS):
//   R = round index; I* = reg set receiving loads for R+2 (issued FIRST);
//   S* = reg set holding R+1's data (loaded a full round ago) -> staged to Bb[bufW].
// MFMA is operand-SWAPPED: mfma(holo_frag, content_frag) so that
//   output col = lane&31 = content row (w*32+ml), output reg-row = holo index
//   rrow = (reg&3) + 8*(reg>>2) + 4*half  -> each lane holds 16 sims of its own row.
#define ROUND_BODY(R, I0,I1,I2,I3,IS, S0,S1,S2,S3,SS)                               \
  do {                                                                              \
    { /* issue loads for round (R)+2 */                                             \
      int g  = n0 + ((R)+2)*NT + srow;                                              \
      int gc = (g < CAP) ? g : (CAP-1);                                             \
      int gb = gc*64 + scol*4;                                                      \
      I0 = hf4[gb+0]; I1 = hf4[gb+1]; I2 = hf4[gb+2]; I3 = hf4[gb+3];               \
      if (t < NT){                                                                  \
        int sidx = n0 + ((R)+2)*NT + t;                                             \
        IS = stren[(sidx < CAP) ? sidx : (CAP-1)];                                  \
      }                                                                             \
    }                                                                               \
    { /* MFMA over K=256 from Bb[bufR] (A = holo tile, B = content frags) */        \
      f32x16 acc = {0.f,0.f,0.f,0.f,0.f,0.f,0.f,0.f,                                \
                    0.f,0.f,0.f,0.f,0.f,0.f,0.f,0.f};                               \
      const int bbase = ml*32;                                                      \
      const int kxor  = ml & 7;                                                     \
      _Pragma("unroll")                                                             \
      for (int ks = 0; ks < 16; ++ks){                                              \
        FragCvt fb; fb.u = Bb[bufR][bbase + ((ks*2 + half) ^ kxor)];                \
        acc = __builtin_amdgcn_mfma_f32_32x32x16_bf16(fb.v, afrag[ks], acc, 0,0,0); \
      }                                                                             \
      /* strengths for this lane's 16 holo rows: rows 8g+4*half..+3 = f4[2g+half] */\
      const float4* s4 = (const float4*)strenb[bufR];                               \
      float4 sg0 = s4[0 + half], sg1 = s4[2 + half],                                \
             sg2 = s4[4 + half], sg3 = s4[6 + half];                                \
      float sv[16];                                                                 \
      sv[ 0]=acc[ 0]*sg0.x; sv[ 1]=acc[ 1]*sg0.y; sv[ 2]=acc[ 2]*sg0.z;             \
      sv[ 3]=acc[ 3]*sg0.w; sv[ 4]=acc[ 4]*sg1.x; sv[ 5]=acc[ 5]*sg1.y;             \
      sv[ 6]=acc[ 6]*sg1.z; sv[ 7]=acc[ 7]*sg1.w; sv[ 8]=acc[ 8]*sg2.x;             \
      sv[ 9]=acc[ 9]*sg2.y; sv[10]=acc[10]*sg2.z; sv[11]=acc[11]*sg2.w;             \
      sv[12]=acc[12]*sg3.x; sv[13]=acc[13]*sg3.y; sv[14]=acc[14]*sg3.z;             \
      sv[15]=acc[15]*sg3.w;                                                         \
      /* selection: this lane's 16 values, global idx = nbase + off(j) */           \
      const int nbase = n0 + (R)*NT;                                                \
      const bool full = (nbase + NT) <= CAP;                                        \
      unsigned pend = 0u;                                                           \
      _Pragma("unroll")                                                             \
      for (int j = 0; j < 16; ++j){                                                 \
        int offj = (j & 3) + 8*(j >> 2) + 4*half;                                   \
        bool ok = (sv[j] > minv) && (full || (nbase + offj) < CAP);                 \
        pend |= ok ? (1u << j) : 0u;                                                \
      }                                                                             \
      while (__any(pend != 0u)){                                                    \
        if (pend){                                                                  \
          int j = __builtin_ctz(pend);                                              \
          pend &= pend - 1u;                                                        \
          float v = -INFINITY;                                                      \
          _Pragma("unroll")                                                         \
          for (int q = 0; q < 16; ++q) v = (q == j) ? sv[q] : v;                    \
          if (v > minv){                                                            \
            int gi = nbase + (j & 3) + 8*(j >> 2) + 4*half;                         \
            list_insert(tv, ti, minv, mins, v, gi);                                 \
          }                                                                         \
        }                                                                           \
      }                                                                             \
    }                                                                               \
    { /* stage round (R)+1 (S-set, one round old) into Bb[bufW] */                  \
      int kc0 = scol*2;                                                             \
      Bb[bufW][srow*32 + ((kc0  ) ^ (srow&7))] = pack8(S0, S1);                     \
      Bb[bufW][srow*32 + ((kc0+1) ^ (srow&7))] = pack8(S2, S3);                     \
      if (t < NT) strenb[bufW][t] = SS;                                             \
    }                                                                               \
    __syncthreads();                                                                \
    bufR = (bufR == 2) ? 0 : bufR + 1;                                              \
    bufW = (bufW == 2) ? 0 : bufW + 1;                                              \
  } while (0)

// ---------------- Phase 1: streamed bf16-MFMA sims + per-block top-16 ----------------
__global__ __launch_bounds__(T1) void k_score(
    const float* __restrict__ content, const float* __restrict__ holo,
    const float* __restrict__ stren, float* __restrict__ cand_val,
    int* __restrict__ cand_idx)
{
  // B staged as 16-B frag chunks: chunk (n, kc) at [n*32 + (kc ^ (n&7))]
  __shared__ uint4 Bb[3][NT*32];          // 3 x 16 KB (triple-buffered, depth-2 prefetch)
  __shared__ float strenb[3][NT];         // strengths, triple-buffered

  const int t    = threadIdx.x;
  const int lane = t & 63;
  const int w    = t >> 6;       // wave 0..7 -> content rows [32w,32w+32)
  const int half = lane >> 5;
  const int ml   = lane & 31;

  // content fragments in registers, bf16, all K=256 (16 ksteps).
  // Lane layout (row w*32+ml, k at ks*16 + half*8) serves as the MFMA *B* operand.
  bf16x8 afrag[16];
  {
    const float4* cf4 = (const float4*)content;
    int base = (w*32 + ml)*64 + half*2;   // float4 units
    #pragma unroll
    for (int ks = 0; ks < 16; ++ks){
      float4 p0 = cf4[base + ks*4 + 0];
      float4 p1 = cf4[base + ks*4 + 1];
      FragCvt fc; fc.u = pack8(p0, p1);
      afrag[ks] = fc.v;
    }
  }

  // per-lane top-16 of this lane's half of row (w*32+ml)'s n-stream
  float tv[TOPB]; int ti[TOPB];
  #pragma unroll
  for (int q = 0; q < TOPB; ++q){ tv[q] = -INFINITY; ti[q] = 0; }
  float minv = -INFINITY; int mins = 0;

  const int n0 = blockIdx.x * CHUNK;

  // staging map: thread -> (row srow, 16-float chunk scol)
  const int srow = t >> 4;
  const int scol = t & 15;
  const float4* hf4 = (const float4*)holo;

  // depth-2 prefetch register sets: data for round k lives in set (k&1)
  float4 a0, a1, a2, a3, b0, b1, b2, b3;
  float  sa = 0.f, sb = 0.f;
  { // prologue: issue r0 -> A and r1 -> B back-to-back, then stage r0
    int g  = n0 + srow;
    int gc = (g < CAP) ? g : (CAP-1);
    int gb = gc*64 + scol*4;
    a0 = hf4[gb+0]; a1 = hf4[gb+1]; a2 = hf4[gb+2]; a3 = hf4[gb+3];
    g  = n0 + NT + srow;
    gc = (g < CAP) ? g : (CAP-1);
    gb = gc*64 + scol*4;
    b0 = hf4[gb+0]; b1 = hf4[gb+1]; b2 = hf4[gb+2]; b3 = hf4[gb+3];
    if (t < NT){
      int s0 = n0 + t;
      sa = stren[(s0 < CAP) ? s0 : (CAP-1)];
      int s1 = n0 + NT + t;
      sb = stren[(s1 < CAP) ? s1 : (CAP-1)];
    }
    int kc0 = scol*2;
    Bb[0][srow*32 + ((kc0  ) ^ (srow&7))] = pack8(a0, a1);
    Bb[0][srow*32 + ((kc0+1) ^ (srow&7))] = pack8(a2, a3);
    if (t < NT) strenb[0][t] = sa;
  }
  __syncthreads();

  int bufR = 0, bufW = 1;
  for (int r = 0; r < ROUNDS-1; r += 2){
    ROUND_BODY(r,   a0,a1,a2,a3,sa,  b0,b1,b2,b3,sb);  // even: issue->A, stage<-B
    ROUND_BODY(r+1, b0,b1,b2,b3,sb,  a0,a1,a2,a3,sa);  // odd:  issue->B, stage<-A
  }
  // tail round 30 (even parity: issue->A, stage<-B)
  ROUND_BODY(ROUNDS-1, a0,a1,a2,a3,sa,  b0,b1,b2,b3,sb);

  // merge the two half-lists of each row (lanes ml and ml+32 of the same wave)
  #pragma unroll
  for (int q = 0; q < TOPB; ++q){
    float ov = __shfl_xor(tv[q], 32);
    int   oi = __shfl_xor(ti[q], 32);
    if (half == 0 && ov > minv) list_insert(tv, ti, minv, mins, ov, oi);
  }
  if (half == 0){
    int m    = w*32 + ml;
    int base = m*(G1*TOPB) + blockIdx.x*TOPB;
    #pragma unroll
    for (int q = 0; q < TOPB; ++q){
      cand_val[base+q] = tv[q];
      cand_idx[base+q] = ti[q];
    }
  }
}

// ---------------- Phase 2: merge 8192 candidates/row -> fp64 rescore 32 -> exact top-10 ----------------
__global__ void k_merge(const float* __restrict__ content,
                        const float* __restrict__ holo,
                        const float* __restrict__ stren,
                        const float* __restrict__ cand_val,
                        const int* __restrict__ cand_idx,
                        int* __restrict__ top_idx)
{
  const int row  = blockIdx.x;
  const int t    = threadIdx.x;   // 256 threads
  const int lane = t & 63;
  const int w    = t >> 6;

  float cv[32]; int ci[32];
  {
    int base = row*(G1*TOPB);
    #pragma unroll
    for (int i = 0; i < 32; ++i){
      int c = i*256 + t;
      cv[i] = cand_val[base + c];
      ci[i] = cand_idx[base + c];
    }
  }
  __shared__ float  lv[4];
  __shared__ int    li[4];
  __shared__ int    sel[MSEL];
  __shared__ double ex[MSEL];
  __shared__ float  cont[D];

  for (int s = 0; s < MSEL; ++s){
    float bv = -INFINITY; int bi = 0x7FFFFFFF;
    #pragma unroll
    for (int i = 0; i < 32; ++i){
      if (cv[i] > bv || (cv[i] == bv && ci[i] < bi)){ bv = cv[i]; bi = ci[i]; }
    }
    #pragma unroll
    for (int off = 1; off < 64; off <<= 1){
      float ov = __shfl_xor(bv, off);
      int   oi = __shfl_xor(bi, off);
      if (ov > bv || (ov == bv && oi < bi)){ bv = ov; bi = oi; }
    }
    if (lane == 0){ lv[w] = bv; li[w] = bi; }
    __syncthreads();
    float wv = lv[0]; int wi = li[0];
    #pragma unroll
    for (int q = 1; q < 4; ++q){
      float ov = lv[q]; int oi = li[q];
      if (ov > wv || (ov == wv && oi < wi)){ wv = ov; wi = oi; }
    }
    if (t == 0) sel[s] = wi;
    #pragma unroll
    for (int i = 0; i < 32; ++i){ if (ci[i] == wi) cv[i] = -INFINITY; }
    __syncthreads();
  }
  if (t < 64) ((float4*)cont)[t] = ((const float4*)content)[row*64 + t];
  __syncthreads();

  // fp64 rescore: wave w -> candidates w*8 .. w*8+7
  const float4* hf4 = (const float4*)holo;
  float4 c4 = ((const float4*)cont)[lane];
  for (int q = 0; q < 8; ++q){
    int s   = w*8 + q;
    int idx = sel[s];
    float4 h4 = hf4[idx*64 + lane];
    double a = (double)h4.x*c4.x + (double)h4.y*c4.y + (double)h4.z*c4.z + (double)h4.w*c4.w;
    #pragma unroll
    for (int off = 1; off < 64; off <<= 1) a += __shfl_xor(a, off);
    if (lane == 0) ex[s] = a * (double)stren[idx];
  }
  __syncthreads();
  if (t == 0){
    unsigned used = 0;
    for (int r = 0; r < TOPK; ++r){
      int best = -1;
      for (int c = 0; c < MSEL; ++c){
        if (used & (1u << c)) continue;
        if (best < 0 || ex[c] > ex[best] || (ex[c] == ex[best] && sel[c] < sel[best])) best = c;
      }
      used |= (1u << best);
      top_idx[row*16 + r] = sel[best];
    }
  }
}

// ---------------- Phase 3: fp32 q/k/v + attention + out-proj ----------------
__global__ __launch_bounds__(512) void k_attn(
    const float* __restrict__ content, const float* __restrict__ holo,
    const float* __restrict__ inw, const float* __restrict__ inb,
    const float* __restrict__ outw, const float* __restrict__ outb,
    const int* __restrict__ top_idx, float* __restrict__ out)
{
  const int b = blockIdx.x;
  const int t = threadIdx.x;
  __shared__ float cont[D];
  __shared__ float mem_s[TOPK*D];
  __shared__ float q_s[D];
  __shared__ float k_s[TOPK*D];
  __shared__ float v_s[TOPK*D];
  __shared__ float sc[H*TOPK];
  __shared__ float at[H*TOPK];
  __shared__ float ctx[D];

  if (t < 64) ((float4*)cont)[t] = ((const float4*)content)[b*64 + t];
  for (int i = t; i < TOPK*D; i += 512){
    int j = i >> 8; int d = i & 255;
    mem_s[i] = holo[(size_t)top_idx[b*16 + j]*D + d];
  }
  __syncthreads();

  const float4* wf4 = (const float4*)inw;
  if (t < 256){ // q projection
    float a = 0.f;
    const float4* c4p = (const float4*)cont;
    #pragma unroll 8
    for (int dc = 0; dc < 64; ++dc){
      float4 wv = wf4[t*64 + dc];
      float4 cc = c4p[dc];
      a += wv.x*cc.x + wv.y*cc.y + wv.z*cc.z + wv.w*cc.w;
    }
    q_s[t] = a + inb[t];
  }
  { // k (threads 0..255) and v (threads 256..511), 10 accumulators each
    int i    = (t < 256) ? t : (t - 256);
    int wrow = (t < 256) ? (256 + i) : (512 + i);
    float a[10];
    #pragma unroll
    for (int j = 0; j < 10; ++j) a[j] = 0.f;
    const float4* m4 = (const float4*)mem_s;
    for (int dc = 0; dc < 64; ++dc){
      float4 wv = wf4[wrow*64 + dc];
      #pragma unroll
      for (int j = 0; j < 10; ++j){
        float4 mm = m4[j*64 + dc];
        a[j] += wv.x*mm.x + wv.y*mm.y + wv.z*mm.z + wv.w*mm.w;
      }
    }
    float bias = inb[wrow];
    if (t < 256){
      #pragma unroll
      for (int j = 0; j < 10; ++j) k_s[j*256 + i] = a[j] + bias;
    } else {
      #pragma unroll
      for (int j = 0; j < 10; ++j) v_s[j*256 + i] = a[j] + bias;
    }
  }
  __syncthreads();
  if (t < H*TOPK){
    int h = t / TOPK, j = t % TOPK;
    float a = 0.f;
    #pragma unroll
    for (int d = 0; d < HD; ++d) a += q_s[h*HD + d] * k_s[j*256 + h*HD + d];
    sc[t] = a * 0.17677669529663687f;   // 1/sqrt(32)
  }
  __syncthreads();
  if (t < H){
    float m = -INFINITY;
    #pragma unroll
    for (int j = 0; j < 10; ++j) m = fmaxf(m, sc[t*10 + j]);
    float e[10]; float su = 0.f;
    #pragma unroll
    for (int j = 0; j < 10; ++j){ e[j] = expf(sc[t*10 + j] - m); su += e[j]; }
    float inv = 1.f / su;
    #pragma unroll
    for (int j = 0; j < 10; ++j) at[t*10 + j] = e[j]*inv;
  }
  __syncthreads();
  if (t < TOPK){ // attn_weights = mean over heads
    float a = 0.f;
    #pragma unroll
    for (int h = 0; h < H; ++h) a += at[h*10 + t];
    out[BATCH*D + b*TOPK + t] = a * 0.125f;
  }
  if (t < 256){ // ctx
    int h = t >> 5;
    float a = 0.f;
    #pragma unroll
    for (int j = 0; j < 10; ++j) a += at[h*10 + j] * v_s[j*256 + t];
    ctx[t] = a;
  }
  __syncthreads();
  if (t < 256){ // out projection
    const float4* of4 = (const float4*)outw;
    const float4* c4p = (const float4*)ctx;
    float a = 0.f;
    #pragma unroll 8
    for (int dc = 0; dc < 64; ++dc){
      float4 wv = of4[t*64 + dc];
      float4 cc = c4p[dc];
      a += wv.x*cc.x + wv.y*cc.y + wv.z*cc.z + wv.w*cc.w;
    }
    out[b*D + t] = a + outb[t];
  }
}

extern "C" void kernel_launch(void* const* d_in, const int* in_sizes, int n_in,
                              void* d_out, int out_size, void* d_ws, size_t ws_size,
                              hipStream_t stream) {
  const float* content = (const float*)d_in[0];
  const float* holo    = (const float*)d_in[1];
  const float* stren   = (const float*)d_in[2];
  const float* inw     = (const float*)d_in[3];
  const float* inb     = (const float*)d_in[4];
  const float* outw    = (const float*)d_in[5];
  const float* outb    = (const float*)d_in[6];
  float* out = (float*)d_out;

  float* cand_val = (float*)d_ws;                         // BATCH*G1*TOPB floats (8 MB)
  int*   cand_idx = (int*)(cand_val + BATCH*G1*TOPB);     // 8 MB
  int*   top_idx  = (int*)(cand_idx + BATCH*G1*TOPB);     // BATCH*16 ints

  hipLaunchKernelGGL(k_score, dim3(G1), dim3(T1), 0, stream,
                     content, holo, stren, cand_val, cand_idx);
  hipLaunchKernelGGL(k_merge, dim3(BATCH), dim3(256), 0, stream,
                     content, holo, stren, cand_val, cand_idx, top_idx);
  hipLaunchKernelGGL(k_attn, dim3(BATCH), dim3(512), 0, stream,
                     content, holo, inw, inb, outw, outb, top_idx, out);
}

// Round 6
// 1013.881 us; speedup vs baseline: 1.0404x; 1.0404x over previous
//
#include <hip/hip_runtime.h>
#include <hip/hip_bf16.h>
#include <math.h>

#define D      256
#define H      8
#define HD     32
#define TOPK   10
#define CAP    500000
#define BATCH  256

#define G1     256            // phase-1 blocks (1 per CU)
#define T1     512            // phase-1 threads (8 waves)
#define NT     32             // hologram rows per round
#define ROUNDS 62             // even (loop unrolled by 2, no tail)
#define CHUNK  (NT*ROUNDS)    // 1984 rows per block
#define TOPB   16             // per-block per-row candidates (per-half-list size)
#define MSEL   32             // exactly-rescored candidates per row

typedef float  f32x16 __attribute__((ext_vector_type(16)));
typedef __bf16 bf16x8 __attribute__((ext_vector_type(8)));

union FragCvt { uint4 u; bf16x8 v; };

__device__ __forceinline__ unsigned bfpair(float lo, float hi){
  unsigned a = __builtin_bit_cast(unsigned, lo);
  unsigned b = __builtin_bit_cast(unsigned, hi);
  a += 0x7FFFu + ((a >> 16) & 1u);   // RNE to bf16
  b += 0x7FFFu + ((b >> 16) & 1u);
  return (a >> 16) | (b & 0xFFFF0000u);
}
__device__ __forceinline__ uint4 pack8(float4 p0, float4 p1){
  uint4 u;
  u.x = bfpair(p0.x, p0.y); u.y = bfpair(p0.z, p0.w);
  u.z = bfpair(p1.x, p1.y); u.w = bfpair(p1.z, p1.w);
  return u;
}

// register-resident top-16 list: replace current-min slot, rescan min (all static idx)
__device__ __forceinline__ void list_insert(float (&tv)[TOPB], int (&ti)[TOPB],
                                            float &minv, int &mins, float v, int gi){
  #pragma unroll
  for (int q = 0; q < TOPB; ++q){ if (q == mins){ tv[q] = v; ti[q] = gi; } }
  float mv = tv[0]; int ms = 0;
  #pragma unroll
  for (int q = 1; q < TOPB; ++q){
    float x = tv[q];
    if (x < mv){ mv = x; ms = q; }
  }
  minv = mv; mins = ms;
}

// one pipelined round:
//   R   = round index (runtime), PAR = R&1 (compile-time literal per unrolled copy)
//   I*  = reg set receiving loads for R+2 (issued FIRST, max flight time)
//   S*  = reg set holding R+1's data (loaded a full round ago) -> staged to Bb[PAR^1]
// MFMA operand-SWAPPED: mfma(holo_frag, content_frag): out col = lane&31 = content row,
//   out reg-row = holo idx off(j) = (j&3)+8*(j>>2)+4*half -> lane holds 16 sims of its row.
// SELECTION IS PIPELINED ONE ROUND BEHIND: round R selects svp[] (round R-1's scaled
// sims, still in registers) while MFMA(R) is in the matrix pipe -> VALU/MFMA overlap.
// Static-j unrolled insert: sv[j] is a plain register (no extract chain); passing lanes
// insert concurrently under exec-mask; empty slots cost one v_cmp + scalar branch.
#define ROUND_BODY(R, PAR, I0,I1,I2,I3,IS, S0,S1,S2,S3,SS)                          \
  do {                                                                              \
    { /* issue loads for round (R)+2 */                                             \
      int g  = n0 + ((R)+2)*NT + srow;                                              \
      int gc = (g < CAP) ? g : (CAP-1);                                             \
      int gb = gc*64 + scol*4;                                                      \
      I0 = hf4[gb+0]; I1 = hf4[gb+1]; I2 = hf4[gb+2]; I3 = hf4[gb+3];               \
      if (t < NT){                                                                  \
        int sidx = n0 + ((R)+2)*NT + t;                                             \
        IS = stren[(sidx < CAP) ? sidx : (CAP-1)];                                  \
      }                                                                             \
    }                                                                               \
    f32x16 acc = {0.f,0.f,0.f,0.f,0.f,0.f,0.f,0.f,                                  \
                  0.f,0.f,0.f,0.f,0.f,0.f,0.f,0.f};                                 \
    { /* MFMA over K=256 from Bb[PAR] (A = holo tile, B = content frags) */         \
      const int bbase = ml*32;                                                      \
      const int kxor  = ml & 7;                                                     \
      _Pragma("unroll")                                                             \
      for (int ks = 0; ks < 16; ++ks){                                              \
        FragCvt fb; fb.u = Bb[PAR][bbase + ((ks*2 + half) ^ kxor)];                 \
        acc = __builtin_amdgcn_mfma_f32_32x32x16_bf16(fb.v, afrag[ks], acc, 0,0,0); \
      }                                                                             \
    }                                                                               \
    /* select round (R)-1 from svp (register-held) -- overlaps the MFMA chain */    \
    if ((R) > 0){                                                                   \
      const int nbasep = n0 + ((R)-1)*NT;                                           \
      const bool fullp = (nbasep + NT) <= CAP;                                      \
      _Pragma("unroll")                                                             \
      for (int j = 0; j < 16; ++j){                                                 \
        const int offj = (j & 3) + 8*(j >> 2) + 4*half;                             \
        bool ok = (svp[j] > minv) && (fullp || (nbasep + offj) < CAP);              \
        if (ok) list_insert(tv, ti, minv, mins, svp[j], nbasep + offj);             \
      }                                                                             \
    }                                                                               \
    { /* epilogue: scale acc by strengths -> svp (consumed by round (R)+1) */       \
      const float4* s4 = (const float4*)strenb[PAR];                                \
      float4 sg0 = s4[0 + half], sg1 = s4[2 + half],                                \
             sg2 = s4[4 + half], sg3 = s4[6 + half];                                \
      svp[ 0]=acc[ 0]*sg0.x; svp[ 1]=acc[ 1]*sg0.y; svp[ 2]=acc[ 2]*sg0.z;          \
      svp[ 3]=acc[ 3]*sg0.w; svp[ 4]=acc[ 4]*sg1.x; svp[ 5]=acc[ 5]*sg1.y;          \
      svp[ 6]=acc[ 6]*sg1.z; svp[ 7]=acc[ 7]*sg1.w; svp[ 8]=acc[ 8]*sg2.x;          \
      svp[ 9]=acc[ 9]*sg2.y; svp[10]=acc[10]*sg2.z; svp[11]=acc[11]*sg2.w;          \
      svp[12]=acc[12]*sg3.x; svp[13]=acc[13]*sg3.y; svp[14]=acc[14]*sg3.z;          \
      svp[15]=acc[15]*sg3.w;                                                        \
    }                                                                               \
    { /* stage round (R)+1 (S-set, one round old) into Bb[PAR^1] */                 \
      int kc0 = scol*2;                                                             \
      Bb[(PAR)^1][srow*32 + ((kc0  ) ^ (srow&7))] = pack8(S0, S1);                  \
      Bb[(PAR)^1][srow*32 + ((kc0+1) ^ (srow&7))] = pack8(S2, S3);                  \
      if (t < NT) strenb[(PAR)^1][t] = SS;                                          \
    }                                                                               \
    __syncthreads();                                                                \
  } while (0)

// ---------------- Phase 1: streamed bf16-MFMA sims + per-block top-16 ----------------
__global__ __launch_bounds__(T1) void k_score(
    const float* __restrict__ content, const float* __restrict__ holo,
    const float* __restrict__ stren, float* __restrict__ cand_val,
    int* __restrict__ cand_idx)
{
  // B staged as 16-B frag chunks: chunk (n, kc) at [n*32 + (kc ^ (n&7))]
  __shared__ uint4 Bb[2][NT*32];          // 2 x 16 KB (round r reads [r&1], stages [r&1^1])
  __shared__ float strenb[2][NT];         // strengths, double-buffered

  const int t    = threadIdx.x;
  const int lane = t & 63;
  const int w    = t >> 6;       // wave 0..7 -> content rows [32w,32w+32)
  const int half = lane >> 5;
  const int ml   = lane & 31;

  // content fragments in registers, bf16, all K=256 (16 ksteps).
  // Lane layout (row w*32+ml, k at ks*16 + half*8) serves as the MFMA *B* operand.
  bf16x8 afrag[16];
  {
    const float4* cf4 = (const float4*)content;
    int base = (w*32 + ml)*64 + half*2;   // float4 units
    #pragma unroll
    for (int ks = 0; ks < 16; ++ks){
      float4 p0 = cf4[base + ks*4 + 0];
      float4 p1 = cf4[base + ks*4 + 1];
      FragCvt fc; fc.u = pack8(p0, p1);
      afrag[ks] = fc.v;
    }
  }

  // per-lane top-16 of this lane's half of row (w*32+ml)'s n-stream
  float tv[TOPB]; int ti[TOPB];
  #pragma unroll
  for (int q = 0; q < TOPB; ++q){ tv[q] = -INFINITY; ti[q] = 0; }
  float minv = -INFINITY; int mins = 0;

  // previous round's scaled sims (selection pipelined one round behind)
  float svp[16];
  #pragma unroll
  for (int j = 0; j < 16; ++j) svp[j] = -INFINITY;

  const int n0 = blockIdx.x * CHUNK;

  // staging map: thread -> (row srow, 16-float chunk scol)
  const int srow = t >> 4;
  const int scol = t & 15;
  const float4* hf4 = (const float4*)holo;

  // depth-2 prefetch register sets: data for round k lives in set (k&1)
  float4 a0, a1, a2, a3, b0, b1, b2, b3;
  float  sa = 0.f, sb = 0.f;
  { // prologue: issue r0 -> A and r1 -> B back-to-back, then stage r0
    int g  = n0 + srow;
    int gc = (g < CAP) ? g : (CAP-1);
    int gb = gc*64 + scol*4;
    a0 = hf4[gb+0]; a1 = hf4[gb+1]; a2 = hf4[gb+2]; a3 = hf4[gb+3];
    g  = n0 + NT + srow;
    gc = (g < CAP) ? g : (CAP-1);
    gb = gc*64 + scol*4;
    b0 = hf4[gb+0]; b1 = hf4[gb+1]; b2 = hf4[gb+2]; b3 = hf4[gb+3];
    if (t < NT){
      int s0 = n0 + t;
      sa = stren[(s0 < CAP) ? s0 : (CAP-1)];
      int s1 = n0 + NT + t;
      sb = stren[(s1 < CAP) ? s1 : (CAP-1)];
    }
    int kc0 = scol*2;
    Bb[0][srow*32 + ((kc0  ) ^ (srow&7))] = pack8(a0, a1);
    Bb[0][srow*32 + ((kc0+1) ^ (srow&7))] = pack8(a2, a3);
    if (t < NT) strenb[0][t] = sa;
  }
  __syncthreads();

  for (int r = 0; r < ROUNDS; r += 2){
    ROUND_BODY(r,   0, a0,a1,a2,a3,sa,  b0,b1,b2,b3,sb);  // even: issue->A, stage<-B
    ROUND_BODY(r+1, 1, b0,b1,b2,b3,sb,  a0,a1,a2,a3,sa);  // odd:  issue->B, stage<-A
  }
  // tail: select the final round's sims (held in svp)
  {
    const int nbasep = n0 + (ROUNDS-1)*NT;
    const bool fullp = (nbasep + NT) <= CAP;
    #pragma unroll
    for (int j = 0; j < 16; ++j){
      const int offj = (j & 3) + 8*(j >> 2) + 4*half;
      bool ok = (svp[j] > minv) && (fullp || (nbasep + offj) < CAP);
      if (ok) list_insert(tv, ti, minv, mins, svp[j], nbasep + offj);
    }
  }

  // merge the two half-lists of each row (lanes ml and ml+32 of the same wave)
  #pragma unroll
  for (int q = 0; q < TOPB; ++q){
    float ov = __shfl_xor(tv[q], 32);
    int   oi = __shfl_xor(ti[q], 32);
    if (half == 0 && ov > minv) list_insert(tv, ti, minv, mins, ov, oi);
  }
  if (half == 0){
    int m    = w*32 + ml;
    int base = m*(G1*TOPB) + blockIdx.x*TOPB;
    #pragma unroll
    for (int q = 0; q < TOPB; ++q){
      cand_val[base+q] = tv[q];
      cand_idx[base+q] = ti[q];
    }
  }
}

// ---------------- Phase 2: merge 4096 candidates/row -> fp64 rescore 32 -> exact top-10 ----------------
__global__ void k_merge(const float* __restrict__ content,
                        const float* __restrict__ holo,
                        const float* __restrict__ stren,
                        const float* __restrict__ cand_val,
                        const int* __restrict__ cand_idx,
                        int* __restrict__ top_idx)
{
  const int row  = blockIdx.x;
  const int t    = threadIdx.x;   // 256 threads
  const int lane = t & 63;
  const int w    = t >> 6;

  float cv[16]; int ci[16];
  {
    int base = row*(G1*TOPB);
    #pragma unroll
    for (int i = 0; i < 16; ++i){
      int c = i*256 + t;
      cv[i] = cand_val[base + c];
      ci[i] = cand_idx[base + c];
    }
  }
  __shared__ float  lv[4];
  __shared__ int    li[4];
  __shared__ int    sel[MSEL];
  __shared__ double ex[MSEL];
  __shared__ float  cont[D];

  for (int s = 0; s < MSEL; ++s){
    float bv = -INFINITY; int bi = 0x7FFFFFFF;
    #pragma unroll
    for (int i = 0; i < 16; ++i){
      if (cv[i] > bv || (cv[i] == bv && ci[i] < bi)){ bv = cv[i]; bi = ci[i]; }
    }
    #pragma unroll
    for (int off = 1; off < 64; off <<= 1){
      float ov = __shfl_xor(bv, off);
      int   oi = __shfl_xor(bi, off);
      if (ov > bv || (ov == bv && oi < bi)){ bv = ov; bi = oi; }
    }
    if (lane == 0){ lv[w] = bv; li[w] = bi; }
    __syncthreads();
    float wv = lv[0]; int wi = li[0];
    #pragma unroll
    for (int q = 1; q < 4; ++q){
      float ov = lv[q]; int oi = li[q];
      if (ov > wv || (ov == wv && oi < wi)){ wv = ov; wi = oi; }
    }
    if (t == 0) sel[s] = wi;
    #pragma unroll
    for (int i = 0; i < 16; ++i){ if (ci[i] == wi) cv[i] = -INFINITY; }
    __syncthreads();
  }
  if (t < 64) ((float4*)cont)[t] = ((const float4*)content)[row*64 + t];
  __syncthreads();

  // fp64 rescore: wave w -> candidates w*8 .. w*8+7
  const float4* hf4 = (const float4*)holo;
  float4 c4 = ((const float4*)cont)[lane];
  for (int q = 0; q < 8; ++q){
    int s   = w*8 + q;
    int idx = sel[s];
    float4 h4 = hf4[idx*64 + lane];
    double a = (double)h4.x*c4.x + (double)h4.y*c4.y + (double)h4.z*c4.z + (double)h4.w*c4.w;
    #pragma unroll
    for (int off = 1; off < 64; off <<= 1) a += __shfl_xor(a, off);
    if (lane == 0) ex[s] = a * (double)stren[idx];
  }
  __syncthreads();
  if (t == 0){
    unsigned used = 0;
    for (int r = 0; r < TOPK; ++r){
      int best = -1;
      for (int c = 0; c < MSEL; ++c){
        if (used & (1u << c)) continue;
        if (best < 0 || ex[c] > ex[best] || (ex[c] == ex[best] && sel[c] < sel[best])) best = c;
      }
      used |= (1u << best);
      top_idx[row*16 + r] = sel[best];
    }
  }
}

// ---------------- Phase 3: fp32 q/k/v + attention + out-proj ----------------
__global__ __launch_bounds__(512) void k_attn(
    const float* __restrict__ content, const float* __restrict__ holo,
    const float* __restrict__ inw, const float* __restrict__ inb,
    const float* __restrict__ outw, const float* __restrict__ outb,
    const int* __restrict__ top_idx, float* __restrict__ out)
{
  const int b = blockIdx.x;
  const int t = threadIdx.x;
  __shared__ float cont[D];
  __shared__ float mem_s[TOPK*D];
  __shared__ float q_s[D];
  __shared__ float k_s[TOPK*D];
  __shared__ float v_s[TOPK*D];
  __shared__ float sc[H*TOPK];
  __shared__ float at[H*TOPK];
  __shared__ float ctx[D];

  if (t < 64) ((float4*)cont)[t] = ((const float4*)content)[b*64 + t];
  for (int i = t; i < TOPK*D; i += 512){
    int j = i >> 8; int d = i & 255;
    mem_s[i] = holo[(size_t)top_idx[b*16 + j]*D + d];
  }
  __syncthreads();

  const float4* wf4 = (const float4*)inw;
  if (t < 256){ // q projection
    float a = 0.f;
    const float4* c4p = (const float4*)cont;
    #pragma unroll 8
    for (int dc = 0; dc < 64; ++dc){
      float4 wv = wf4[t*64 + dc];
      float4 cc = c4p[dc];
      a += wv.x*cc.x + wv.y*cc.y + wv.z*cc.z + wv.w*cc.w;
    }
    q_s[t] = a + inb[t];
  }
  { // k (threads 0..255) and v (threads 256..511), 10 accumulators each
    int i    = (t < 256) ? t : (t - 256);
    int wrow = (t < 256) ? (256 + i) : (512 + i);
    float a[10];
    #pragma unroll
    for (int j = 0; j < 10; ++j) a[j] = 0.f;
    const float4* m4 = (const float4*)mem_s;
    for (int dc = 0; dc < 64; ++dc){
      float4 wv = wf4[wrow*64 + dc];
      #pragma unroll
      for (int j = 0; j < 10; ++j){
        float4 mm = m4[j*64 + dc];
        a[j] += wv.x*mm.x + wv.y*mm.y + wv.z*mm.z + wv.w*mm.w;
      }
    }
    float bias = inb[wrow];
    if (t < 256){
      #pragma unroll
      for (int j = 0; j < 10; ++j) k_s[j*256 + i] = a[j] + bias;
    } else {
      #pragma unroll
      for (int j = 0; j < 10; ++j) v_s[j*256 + i] = a[j] + bias;
    }
  }
  __syncthreads();
  if (t < H*TOPK){
    int h = t / TOPK, j = t % TOPK;
    float a = 0.f;
    #pragma unroll
    for (int d = 0; d < HD; ++d) a += q_s[h*HD + d] * k_s[j*256 + h*HD + d];
    sc[t] = a * 0.17677669529663687f;   // 1/sqrt(32)
  }
  __syncthreads();
  if (t < H){
    float m = -INFINITY;
    #pragma unroll
    for (int j = 0; j < 10; ++j) m = fmaxf(m, sc[t*10 + j]);
    float e[10]; float su = 0.f;
    #pragma unroll
    for (int j = 0; j < 10; ++j){ e[j] = expf(sc[t*10 + j] - m); su += e[j]; }
    float inv = 1.f / su;
    #pragma unroll
    for (int j = 0; j < 10; ++j) at[t*10 + j] = e[j]*inv;
  }
  __syncthreads();
  if (t < TOPK){ // attn_weights = mean over heads
    float a = 0.f;
    #pragma unroll
    for (int h = 0; h < H; ++h) a += at[h*10 + t];
    out[BATCH*D + b*TOPK + t] = a * 0.125f;
  }
  if (t < 256){ // ctx
    int h = t >> 5;
    float a = 0.f;
    #pragma unroll
    for (int j = 0; j < 10; ++j) a += at[h*10 + j] * v_s[j*256 + t];
    ctx[t] = a;
  }
  __syncthreads();
  if (t < 256){ // out projection
    const float4* of4 = (const float4*)outw;
    const float4* c4p = (const float4*)ctx;
    float a = 0.f;
    #pragma unroll 8
    for (int dc = 0; dc < 64; ++dc){
      float4 wv = of4[t*64 + dc];
      float4 cc = c4p[dc];
      a += wv.x*cc.x + wv.y*cc.y + wv.z*cc.z + wv.w*cc.w;
    }
    out[b*D + t] = a + outb[t];
  }
}

extern "C" void kernel_launch(void* const* d_in, const int* in_sizes, int n_in,
                              void* d_out, int out_size, void* d_ws, size_t ws_size,
                              hipStream_t stream) {
  const float* content = (const float*)d_in[0];
  const float* holo    = (const float*)d_in[1];
  const float* stren   = (const float*)d_in[2];
  const float* inw     = (const float*)d_in[3];
  const float* inb     = (const float*)d_in[4];
  const float* outw    = (const float*)d_in[5];
  const float* outb    = (const float*)d_in[6];
  float* out = (float*)d_out;

  float* cand_val = (float*)d_ws;                         // BATCH*G1*TOPB floats (4 MB)
  int*   cand_idx = (int*)(cand_val + BATCH*G1*TOPB);     // 4 MB
  int*   top_idx  = (int*)(cand_idx + BATCH*G1*TOPB);     // BATCH*16 ints

  hipLaunchKernelGGL(k_score, dim3(G1), dim3(T1), 0, stream,
                     content, holo, stren, cand_val, cand_idx);
  hipLaunchKernelGGL(k_merge, dim3(BATCH), dim3(256), 0, stream,
                     content, holo, stren, cand_val, cand_idx, top_idx);
  hipLaunchKernelGGL(k_attn, dim3(BATCH), dim3(512), 0, stream,
                     content, holo, inw, inb, outw, outb, top_idx, out);
}

// Round 7
// 971.970 us; speedup vs baseline: 1.0853x; 1.0431x over previous
//
#include <hip/hip_runtime.h>
#include <hip/hip_bf16.h>
#include <math.h>

#define D      256
#define H      8
#define HD     32
#define TOPK   10
#define CAP    500000
#define BATCH  256

#define G1     256            // phase-1 blocks (1 per CU)
#define T1     512            // phase-1 threads (8 waves)
#define NT     32             // hologram rows per round
#define ROUNDS 62             // even (loop unrolled by 2, no tail)
#define CHUNK  (NT*ROUNDS)    // 1984 rows per block
#define TOPB   16             // per-block per-row candidates (per-half-list size)
#define MSEL   32             // exactly-rescored candidates per row

typedef float  f32x16 __attribute__((ext_vector_type(16)));
typedef __bf16 bf16x8 __attribute__((ext_vector_type(8)));

union FragCvt { uint4 u; bf16x8 v; };

__device__ __forceinline__ unsigned bfpair(float lo, float hi){
  unsigned a = __builtin_bit_cast(unsigned, lo);
  unsigned b = __builtin_bit_cast(unsigned, hi);
  a += 0x7FFFu + ((a >> 16) & 1u);   // RNE to bf16
  b += 0x7FFFu + ((b >> 16) & 1u);
  return (a >> 16) | (b & 0xFFFF0000u);
}
__device__ __forceinline__ uint4 pack8(float4 p0, float4 p1){
  uint4 u;
  u.x = bfpair(p0.x, p0.y); u.y = bfpair(p0.z, p0.w);
  u.z = bfpair(p1.x, p1.y); u.w = bfpair(p1.z, p1.w);
  return u;
}

// register-resident top-16 list: replace current-min slot, rescan min (all static idx)
__device__ __forceinline__ void list_insert(float (&tv)[TOPB], int (&ti)[TOPB],
                                            float &minv, int &mins, float v, int gi){
  #pragma unroll
  for (int q = 0; q < TOPB; ++q){ if (q == mins){ tv[q] = v; ti[q] = gi; } }
  float mv = tv[0]; int ms = 0;
  #pragma unroll
  for (int q = 1; q < TOPB; ++q){
    float x = tv[q];
    if (x < mv){ mv = x; ms = q; }
  }
  minv = mv; mins = ms;
}

// pend/ctz-batched select over the 16 register values in sv[] (previous round's sims).
// Wave cost = max-over-lanes popcount(pend) insert iterations (NOT 16 x any-lane-hit).
__device__ __forceinline__ void select_regs(const float (&sv)[16], int nbase, int half,
                                            float (&tv)[TOPB], int (&ti)[TOPB],
                                            float &minv, int &mins){
  const bool full = (nbase + NT) <= CAP;
  unsigned pend = 0u;
  #pragma unroll
  for (int j = 0; j < 16; ++j){
    const int offj = (j & 3) + 8*(j >> 2) + 4*half;
    bool ok = (sv[j] > minv) && (full || (nbase + offj) < CAP);
    pend |= ok ? (1u << j) : 0u;
  }
  while (__any(pend != 0u)){
    if (pend){
      int j = __builtin_ctz(pend);
      pend &= pend - 1u;
      float v = -INFINITY;
      #pragma unroll
      for (int q = 0; q < 16; ++q) v = (q == j) ? sv[q] : v;   // static-index extract
      if (v > minv){
        int gi = nbase + (j & 3) + 8*(j >> 2) + 4*half;
        list_insert(tv, ti, minv, mins, v, gi);
      }
    }
  }
}

// one pipelined round:
//   R   = round index, PAR = R&1 (compile-time literal per unrolled copy)
//   depth-1 prefetch: loads for R+1 issued at round top into the single a-set,
//   staged into Bb[PAR^1] at round bottom (vmcnt wait covered by MFMA+select).
// MFMA operand-SWAPPED: mfma(holo_frag, content_frag): out col = lane&31 = content row,
//   out reg-row = holo idx off(j) = (j&3)+8*(j>>2)+4*half -> lane holds 16 sims of its row.
// SELECTION PIPELINED ONE ROUND BEHIND: round R selects svp[] (round R-1's scaled sims,
// register-held) while MFMA(R) occupies the matrix pipe -> VALU/MFMA overlap.
#define ROUND_BODY(R, PAR)                                                          \
  do {                                                                              \
    { /* issue loads for round (R)+1 */                                             \
      int g  = n0 + ((R)+1)*NT + srow;                                              \
      int gc = (g < CAP) ? g : (CAP-1);                                             \
      int gb = gc*64 + scol*4;                                                      \
      a0 = hf4[gb+0]; a1 = hf4[gb+1]; a2 = hf4[gb+2]; a3 = hf4[gb+3];               \
      if (t < NT){                                                                  \
        int sidx = n0 + ((R)+1)*NT + t;                                             \
        sa = stren[(sidx < CAP) ? sidx : (CAP-1)];                                  \
      }                                                                             \
    }                                                                               \
    f32x16 acc = {0.f,0.f,0.f,0.f,0.f,0.f,0.f,0.f,                                  \
                  0.f,0.f,0.f,0.f,0.f,0.f,0.f,0.f};                                 \
    { /* MFMA over K=256 from Bb[PAR] (A = holo tile, B = content frags) */         \
      const int bbase = ml*32;                                                      \
      const int kxor  = ml & 7;                                                     \
      _Pragma("unroll")                                                             \
      for (int ks = 0; ks < 16; ++ks){                                              \
        FragCvt fb; fb.u = Bb[PAR][bbase + ((ks*2 + half) ^ kxor)];                 \
        acc = __builtin_amdgcn_mfma_f32_32x32x16_bf16(fb.v, afrag[ks], acc, 0,0,0); \
      }                                                                             \
    }                                                                               \
    /* select round (R)-1 from svp (register-held) -- overlaps the MFMA chain */    \
    if ((R) > 0) select_regs(svp, n0 + ((R)-1)*NT, half, tv, ti, minv, mins);       \
    { /* epilogue: scale acc by strengths -> svp (consumed by round (R)+1) */       \
      const float4* s4 = (const float4*)strenb[PAR];                                \
      float4 sg0 = s4[0 + half], sg1 = s4[2 + half],                                \
             sg2 = s4[4 + half], sg3 = s4[6 + half];                                \
      svp[ 0]=acc[ 0]*sg0.x; svp[ 1]=acc[ 1]*sg0.y; svp[ 2]=acc[ 2]*sg0.z;          \
      svp[ 3]=acc[ 3]*sg0.w; svp[ 4]=acc[ 4]*sg1.x; svp[ 5]=acc[ 5]*sg1.y;          \
      svp[ 6]=acc[ 6]*sg1.z; svp[ 7]=acc[ 7]*sg1.w; svp[ 8]=acc[ 8]*sg2.x;          \
      svp[ 9]=acc[ 9]*sg2.y; svp[10]=acc[10]*sg2.z; svp[11]=acc[11]*sg2.w;          \
      svp[12]=acc[12]*sg3.x; svp[13]=acc[13]*sg3.y; svp[14]=acc[14]*sg3.z;          \
      svp[15]=acc[15]*sg3.w;                                                        \
    }                                                                               \
    { /* stage round (R)+1 into Bb[PAR^1] */                                        \
      int kc0 = scol*2;                                                             \
      Bb[(PAR)^1][srow*32 + ((kc0  ) ^ (srow&7))] = pack8(a0, a1);                  \
      Bb[(PAR)^1][srow*32 + ((kc0+1) ^ (srow&7))] = pack8(a2, a3);                  \
      if (t < NT) strenb[(PAR)^1][t] = sa;                                          \
    }                                                                               \
    __syncthreads();                                                                \
  } while (0)

// ---------------- Phase 1: streamed bf16-MFMA sims + per-block top-16 ----------------
__global__ __launch_bounds__(T1) void k_score(
    const float* __restrict__ content, const float* __restrict__ holo,
    const float* __restrict__ stren, float* __restrict__ cand_val,
    int* __restrict__ cand_idx)
{
  // B staged as 16-B frag chunks: chunk (n, kc) at [n*32 + (kc ^ (n&7))]
  __shared__ uint4 Bb[2][NT*32];          // 2 x 16 KB (round r reads [r&1], stages [r&1^1])
  __shared__ float strenb[2][NT];         // strengths, double-buffered

  const int t    = threadIdx.x;
  const int lane = t & 63;
  const int w    = t >> 6;       // wave 0..7 -> content rows [32w,32w+32)
  const int half = lane >> 5;
  const int ml   = lane & 31;

  // content fragments in registers, bf16, all K=256 (16 ksteps).
  // Lane layout (row w*32+ml, k at ks*16 + half*8) serves as the MFMA *B* operand.
  bf16x8 afrag[16];
  {
    const float4* cf4 = (const float4*)content;
    int base = (w*32 + ml)*64 + half*2;   // float4 units
    #pragma unroll
    for (int ks = 0; ks < 16; ++ks){
      float4 p0 = cf4[base + ks*4 + 0];
      float4 p1 = cf4[base + ks*4 + 1];
      FragCvt fc; fc.u = pack8(p0, p1);
      afrag[ks] = fc.v;
    }
  }

  // per-lane top-16 of this lane's half of row (w*32+ml)'s n-stream
  float tv[TOPB]; int ti[TOPB];
  #pragma unroll
  for (int q = 0; q < TOPB; ++q){ tv[q] = -INFINITY; ti[q] = 0; }
  float minv = -INFINITY; int mins = 0;

  // previous round's scaled sims (selection pipelined one round behind)
  float svp[16];
  #pragma unroll
  for (int j = 0; j < 16; ++j) svp[j] = -INFINITY;

  const int n0 = blockIdx.x * CHUNK;

  // staging map: thread -> (row srow, 16-float chunk scol)
  const int srow = t >> 4;
  const int scol = t & 15;
  const float4* hf4 = (const float4*)holo;

  // depth-1 prefetch register set
  float4 a0, a1, a2, a3;
  float  sa = 0.f;
  { // prologue: load r0, stage into Bb[0]
    int g  = n0 + srow;
    int gc = (g < CAP) ? g : (CAP-1);
    int gb = gc*64 + scol*4;
    a0 = hf4[gb+0]; a1 = hf4[gb+1]; a2 = hf4[gb+2]; a3 = hf4[gb+3];
    if (t < NT){
      int s0 = n0 + t;
      sa = stren[(s0 < CAP) ? s0 : (CAP-1)];
    }
    int kc0 = scol*2;
    Bb[0][srow*32 + ((kc0  ) ^ (srow&7))] = pack8(a0, a1);
    Bb[0][srow*32 + ((kc0+1) ^ (srow&7))] = pack8(a2, a3);
    if (t < NT) strenb[0][t] = sa;
  }
  __syncthreads();

  for (int r = 0; r < ROUNDS; r += 2){
    ROUND_BODY(r,   0);
    ROUND_BODY(r+1, 1);
  }
  // tail: select the final round's sims (held in svp)
  select_regs(svp, n0 + (ROUNDS-1)*NT, half, tv, ti, minv, mins);

  // merge the two half-lists of each row (lanes ml and ml+32 of the same wave)
  #pragma unroll
  for (int q = 0; q < TOPB; ++q){
    float ov = __shfl_xor(tv[q], 32);
    int   oi = __shfl_xor(ti[q], 32);
    if (half == 0 && ov > minv) list_insert(tv, ti, minv, mins, ov, oi);
  }
  if (half == 0){
    int m    = w*32 + ml;
    int base = m*(G1*TOPB) + blockIdx.x*TOPB;
    #pragma unroll
    for (int q = 0; q < TOPB; ++q){
      cand_val[base+q] = tv[q];
      cand_idx[base+q] = ti[q];
    }
  }
}

// ---------------- Phase 2: merge 4096 candidates/row -> fp64 rescore 32 -> exact top-10 ----------------
__global__ void k_merge(const float* __restrict__ content,
                        const float* __restrict__ holo,
                        const float* __restrict__ stren,
                        const float* __restrict__ cand_val,
                        const int* __restrict__ cand_idx,
                        int* __restrict__ top_idx)
{
  const int row  = blockIdx.x;
  const int t    = threadIdx.x;   // 256 threads
  const int lane = t & 63;
  const int w    = t >> 6;

  float cv[16]; int ci[16];
  {
    int base = row*(G1*TOPB);
    #pragma unroll
    for (int i = 0; i < 16; ++i){
      int c = i*256 + t;
      cv[i] = cand_val[base + c];
      ci[i] = cand_idx[base + c];
    }
  }
  __shared__ float  lv[4];
  __shared__ int    li[4];
  __shared__ int    sel[MSEL];
  __shared__ double ex[MSEL];
  __shared__ float  cont[D];

  for (int s = 0; s < MSEL; ++s){
    float bv = -INFINITY; int bi = 0x7FFFFFFF;
    #pragma unroll
    for (int i = 0; i < 16; ++i){
      if (cv[i] > bv || (cv[i] == bv && ci[i] < bi)){ bv = cv[i]; bi = ci[i]; }
    }
    #pragma unroll
    for (int off = 1; off < 64; off <<= 1){
      float ov = __shfl_xor(bv, off);
      int   oi = __shfl_xor(bi, off);
      if (ov > bv || (ov == bv && oi < bi)){ bv = ov; bi = oi; }
    }
    if (lane == 0){ lv[w] = bv; li[w] = bi; }
    __syncthreads();
    float wv = lv[0]; int wi = li[0];
    #pragma unroll
    for (int q = 1; q < 4; ++q){
      float ov = lv[q]; int oi = li[q];
      if (ov > wv || (ov == wv && oi < wi)){ wv = ov; wi = oi; }
    }
    if (t == 0) sel[s] = wi;
    #pragma unroll
    for (int i = 0; i < 16; ++i){ if (ci[i] == wi) cv[i] = -INFINITY; }
    __syncthreads();
  }
  if (t < 64) ((float4*)cont)[t] = ((const float4*)content)[row*64 + t];
  __syncthreads();

  // fp64 rescore: wave w -> candidates w*8 .. w*8+7
  const float4* hf4 = (const float4*)holo;
  float4 c4 = ((const float4*)cont)[lane];
  for (int q = 0; q < 8; ++q){
    int s   = w*8 + q;
    int idx = sel[s];
    float4 h4 = hf4[idx*64 + lane];
    double a = (double)h4.x*c4.x + (double)h4.y*c4.y + (double)h4.z*c4.z + (double)h4.w*c4.w;
    #pragma unroll
    for (int off = 1; off < 64; off <<= 1) a += __shfl_xor(a, off);
    if (lane == 0) ex[s] = a * (double)stren[idx];
  }
  __syncthreads();
  if (t == 0){
    unsigned used = 0;
    for (int r = 0; r < TOPK; ++r){
      int best = -1;
      for (int c = 0; c < MSEL; ++c){
        if (used & (1u << c)) continue;
        if (best < 0 || ex[c] > ex[best] || (ex[c] == ex[best] && sel[c] < sel[best])) best = c;
      }
      used |= (1u << best);
      top_idx[row*16 + r] = sel[best];
    }
  }
}

// ---------------- Phase 3: fp32 q/k/v + attention + out-proj ----------------
__global__ __launch_bounds__(512) void k_attn(
    const float* __restrict__ content, const float* __restrict__ holo,
    const float* __restrict__ inw, const float* __restrict__ inb,
    const float* __restrict__ outw, const float* __restrict__ outb,
    const int* __restrict__ top_idx, float* __restrict__ out)
{
  const int b = blockIdx.x;
  const int t = threadIdx.x;
  __shared__ float cont[D];
  __shared__ float mem_s[TOPK*D];
  __shared__ float q_s[D];
  __shared__ float k_s[TOPK*D];
  __shared__ float v_s[TOPK*D];
  __shared__ float sc[H*TOPK];
  __shared__ float at[H*TOPK];
  __shared__ float ctx[D];

  if (t < 64) ((float4*)cont)[t] = ((const float4*)content)[b*64 + t];
  for (int i = t; i < TOPK*D; i += 512){
    int j = i >> 8; int d = i & 255;
    mem_s[i] = holo[(size_t)top_idx[b*16 + j]*D + d];
  }
  __syncthreads();

  const float4* wf4 = (const float4*)inw;
  if (t < 256){ // q projection
    float a = 0.f;
    const float4* c4p = (const float4*)cont;
    #pragma unroll 8
    for (int dc = 0; dc < 64; ++dc){
      float4 wv = wf4[t*64 + dc];
      float4 cc = c4p[dc];
      a += wv.x*cc.x + wv.y*cc.y + wv.z*cc.z + wv.w*cc.w;
    }
    q_s[t] = a + inb[t];
  }
  { // k (threads 0..255) and v (threads 256..511), 10 accumulators each
    int i    = (t < 256) ? t : (t - 256);
    int wrow = (t < 256) ? (256 + i) : (512 + i);
    float a[10];
    #pragma unroll
    for (int j = 0; j < 10; ++j) a[j] = 0.f;
    const float4* m4 = (const float4*)mem_s;
    for (int dc = 0; dc < 64; ++dc){
      float4 wv = wf4[wrow*64 + dc];
      #pragma unroll
      for (int j = 0; j < 10; ++j){
        float4 mm = m4[j*64 + dc];
        a[j] += wv.x*mm.x + wv.y*mm.y + wv.z*mm.z + wv.w*mm.w;
      }
    }
    float bias = inb[wrow];
    if (t < 256){
      #pragma unroll
      for (int j = 0; j < 10; ++j) k_s[j*256 + i] = a[j] + bias;
    } else {
      #pragma unroll
      for (int j = 0; j < 10; ++j) v_s[j*256 + i] = a[j] + bias;
    }
  }
  __syncthreads();
  if (t < H*TOPK){
    int h = t / TOPK, j = t % TOPK;
    float a = 0.f;
    #pragma unroll
    for (int d = 0; d < HD; ++d) a += q_s[h*HD + d] * k_s[j*256 + h*HD + d];
    sc[t] = a * 0.17677669529663687f;   // 1/sqrt(32)
  }
  __syncthreads();
  if (t < H){
    float m = -INFINITY;
    #pragma unroll
    for (int j = 0; j < 10; ++j) m = fmaxf(m, sc[t*10 + j]);
    float e[10]; float su = 0.f;
    #pragma unroll
    for (int j = 0; j < 10; ++j){ e[j] = expf(sc[t*10 + j] - m); su += e[j]; }
    float inv = 1.f / su;
    #pragma unroll
    for (int j = 0; j < 10; ++j) at[t*10 + j] = e[j]*inv;
  }
  __syncthreads();
  if (t < TOPK){ // attn_weights = mean over heads
    float a = 0.f;
    #pragma unroll
    for (int h = 0; h < H; ++h) a += at[h*10 + t];
    out[BATCH*D + b*TOPK + t] = a * 0.125f;
  }
  if (t < 256){ // ctx
    int h = t >> 5;
    float a = 0.f;
    #pragma unroll
    for (int j = 0; j < 10; ++j) a += at[h*10 + j] * v_s[j*256 + t];
    ctx[t] = a;
  }
  __syncthreads();
  if (t < 256){ // out projection
    const float4* of4 = (const float4*)outw;
    const float4* c4p = (const float4*)ctx;
    float a = 0.f;
    #pragma unroll 8
    for (int dc = 0; dc < 64; ++dc){
      float4 wv = of4[t*64 + dc];
      float4 cc = c4p[dc];
      a += wv.x*cc.x + wv.y*cc.y + wv.z*cc.z + wv.w*cc.w;
    }
    out[b*D + t] = a + outb[t];
  }
}

extern "C" void kernel_launch(void* const* d_in, const int* in_sizes, int n_in,
                              void* d_out, int out_size, void* d_ws, size_t ws_size,
                              hipStream_t stream) {
  const float* content = (const float*)d_in[0];
  const float* holo    = (const float*)d_in[1];
  const float* stren   = (const float*)d_in[2];
  const float* inw     = (const float*)d_in[3];
  const float* inb     = (const float*)d_in[4];
  const float* outw    = (const float*)d_in[5];
  const float* outb    = (const float*)d_in[6];
  float* out = (float*)d_out;

  float* cand_val = (float*)d_ws;                         // BATCH*G1*TOPB floats (4 MB)
  int*   cand_idx = (int*)(cand_val + BATCH*G1*TOPB);     // 4 MB
  int*   top_idx  = (int*)(cand_idx + BATCH*G1*TOPB);     // BATCH*16 ints

  hipLaunchKernelGGL(k_score, dim3(G1), dim3(T1), 0, stream,
                     content, holo, stren, cand_val, cand_idx);
  hipLaunchKernelGGL(k_merge, dim3(BATCH), dim3(256), 0, stream,
                     content, holo, stren, cand_val, cand_idx, top_idx);
  hipLaunchKernelGGL(k_attn, dim3(BATCH), dim3(512), 0, stream,
                     content, holo, inw, inb, outw, outb, top_idx, out);
}

// Round 8
// 889.401 us; speedup vs baseline: 1.1860x; 1.0928x over previous
//
#include <hip/hip_runtime.h>
#include <hip/hip_bf16.h>
#include <math.h>

#define D      256
#define H      8
#define HD     32
#define TOPK   10
#define CAP    500000
#define BATCH  256

#define G1     256            // phase-1 blocks (1 per CU)
#define T1     512            // phase-1 threads (8 waves)
#define NT     32             // hologram rows per round
#define ROUNDS 62
#define CHUNK  (NT*ROUNDS)    // 1984 rows per block
#define TOPB   16             // per-block per-row candidates (also per-half-list size)
#define MSEL   32             // exactly-rescored candidates per row

typedef float  f32x16 __attribute__((ext_vector_type(16)));
typedef __bf16 bf16x8 __attribute__((ext_vector_type(8)));

union FragCvt { uint4 u; bf16x8 v; };

__device__ __forceinline__ unsigned bfpair(float lo, float hi){
  unsigned a = __builtin_bit_cast(unsigned, lo);
  unsigned b = __builtin_bit_cast(unsigned, hi);
  a += 0x7FFFu + ((a >> 16) & 1u);   // RNE to bf16
  b += 0x7FFFu + ((b >> 16) & 1u);
  return (a >> 16) | (b & 0xFFFF0000u);
}
__device__ __forceinline__ uint4 pack8(float4 p0, float4 p1){
  uint4 u;
  u.x = bfpair(p0.x, p0.y); u.y = bfpair(p0.z, p0.w);
  u.z = bfpair(p1.x, p1.y); u.w = bfpair(p1.z, p1.w);
  return u;
}

// register-resident top-16 list: replace current-min slot, rescan min (all static idx)
__device__ __forceinline__ void list_insert(float (&tv)[TOPB], int (&ti)[TOPB],
                                            float &minv, int &mins, float v, int gi){
  #pragma unroll
  for (int q = 0; q < TOPB; ++q){ if (q == mins){ tv[q] = v; ti[q] = gi; } }
  float mv = tv[0]; int ms = 0;
  #pragma unroll
  for (int q = 1; q < TOPB; ++q){
    float x = tv[q];
    if (x < mv){ mv = x; ms = q; }
  }
  minv = mv; mins = ms;
}

// scan 16 sims values (constant trip, pipelined ds_reads), batched rare inserts
__device__ __forceinline__ void select16(const float* __restrict__ srow, int gbase, int lim,
                                         float (&tv)[TOPB], int (&ti)[TOPB],
                                         float &minv, int &mins){
  float sv[16];
  #pragma unroll
  for (int j = 0; j < 16; ++j) sv[j] = srow[j];
  unsigned pend = 0u;
  #pragma unroll
  for (int j = 0; j < 16; ++j) pend |= (sv[j] > minv) ? (1u << j) : 0u;
  unsigned limmask = (lim >= 16) ? 0xFFFFu : ((lim <= 0) ? 0u : ((1u << lim) - 1u));
  pend &= limmask;
  while (__any(pend != 0u)){
    if (pend){
      int j = __builtin_ctz(pend);
      pend &= pend - 1u;
      float v = -INFINITY;
      #pragma unroll
      for (int q = 0; q < 16; ++q) v = (q == j) ? sv[q] : v;   // static-index extract
      if (v > minv) list_insert(tv, ti, minv, mins, v, gbase + j);
    }
  }
}

// ---------------- Phase 1: streamed bf16-MFMA sims + per-block top-16 ----------------
__global__ __launch_bounds__(T1) void k_score(
    const float* __restrict__ content, const float* __restrict__ holo,
    const float* __restrict__ stren, float* __restrict__ cand_val,
    int* __restrict__ cand_idx)
{
  // B staged as 16-B frag chunks: chunk (n, kc) at [n*32 + (kc ^ (n&7))]
  __shared__ uint4 Bb[2][NT*32];          // 2 x 16 KB
  __shared__ float simsb[2][BATCH*33];    // 2 x 33.8 KB, double-buffered (33 pad: conflict-free)
  __shared__ float strenb[2][NT];         // strengths tile, double-buffered

  const int t    = threadIdx.x;
  const int lane = t & 63;
  const int w    = t >> 6;       // wave 0..7 -> m-tile rows [32w,32w+32)
  const int half = lane >> 5;
  const int ml   = lane & 31;

  const int row = t & 255;        // selection: 2 threads per row
  const int c0  = (t >> 8) * 16;  // column half [c0, c0+16) of each round

  // A fragments (content rows) in registers, bf16, all K=256 (16 ksteps)
  bf16x8 afrag[16];
  {
    const float4* cf4 = (const float4*)content;
    int base = (w*32 + ml)*64 + half*2;   // float4 units
    #pragma unroll
    for (int ks = 0; ks < 16; ++ks){
      float4 p0 = cf4[base + ks*4 + 0];
      float4 p1 = cf4[base + ks*4 + 1];
      FragCvt fc; fc.u = pack8(p0, p1);
      afrag[ks] = fc.v;
    }
  }

  // per-thread top-16 (of this thread's half-row stream) in registers
  float tv[TOPB]; int ti[TOPB];
  #pragma unroll
  for (int q = 0; q < TOPB; ++q){ tv[q] = -INFINITY; ti[q] = 0; }
  float minv = -INFINITY; int mins = 0;

  const int n0 = blockIdx.x * CHUNK;

  // staging map: thread -> (row srow, 16-float chunk scol)
  const int srow = t >> 4;
  const int scol = t & 15;
  const float4* hf4 = (const float4*)holo;

  float4 st0, st1, st2, st3;
  { // prologue: round 0
    int g  = n0 + srow;
    int gc = (g < CAP) ? g : (CAP-1);
    int gb = gc*64 + scol*4;
    st0 = hf4[gb+0]; st1 = hf4[gb+1]; st2 = hf4[gb+2]; st3 = hf4[gb+3];
    int kc0 = scol*2;
    Bb[0][srow*32 + ((kc0  ) ^ (srow&7))] = pack8(st0, st1);
    Bb[0][srow*32 + ((kc0+1) ^ (srow&7))] = pack8(st2, st3);
    if (t < NT){
      int s0 = n0 + t;
      strenb[0][t] = stren[(s0 < CAP) ? s0 : (CAP-1)];
    }
  }
  __syncthreads();

  for (int r = 0; r < ROUNDS; ++r){
    const int buf = r & 1;
    float sp;
    { // prefetch round r+1 into registers (clamped)
      int g  = n0 + (r+1)*NT + srow;
      int gc = (g < CAP) ? g : (CAP-1);
      int gb = gc*64 + scol*4;
      st0 = hf4[gb+0]; st1 = hf4[gb+1]; st2 = hf4[gb+2]; st3 = hf4[gb+3];
      if (t < NT){
        int s1 = n0 + (r+1)*NT + t;
        sp = stren[(s1 < CAP) ? s1 : (CAP-1)];
      }
    }
    // MFMA over K=256
    f32x16 acc = {0.f,0.f,0.f,0.f,0.f,0.f,0.f,0.f,0.f,0.f,0.f,0.f,0.f,0.f,0.f,0.f};
    const int bbase = ml*32;
    const int kxor  = ml & 7;
    #pragma unroll
    for (int ks = 0; ks < 16; ++ks){
      FragCvt fb; fb.u = Bb[buf][bbase + ((ks*2 + half) ^ kxor)];
      acc = __builtin_amdgcn_mfma_f32_32x32x16_bf16(afrag[ks], fb.v, acc, 0, 0, 0);
    }
    // epilogue: sims*stren -> LDS[buf] (C layout: col=lane&31, row=(reg&3)+8*(reg>>2)+4*half)
    {
      float stren_ls = strenb[buf][ml];
      #pragma unroll
      for (int reg = 0; reg < 16; ++reg){
        int rrow = (reg & 3) + 8*(reg >> 2) + 4*half;
        simsb[buf][(w*32 + rrow)*33 + ml] = acc[reg] * stren_ls;
      }
    }
    // selection of round r-1 from the other sims buffer (overlaps MFMA/loads; no extra barrier)
    if (r > 0){
      int nbp = n0 + (r-1)*NT;
      select16(&simsb[buf^1][row*33 + c0], nbp + c0, CAP - (nbp + c0), tv, ti, minv, mins);
    }
    // stage r+1 into other buffer
    {
      int kc0 = scol*2;
      Bb[buf^1][srow*32 + ((kc0  ) ^ (srow&7))] = pack8(st0, st1);
      Bb[buf^1][srow*32 + ((kc0+1) ^ (srow&7))] = pack8(st2, st3);
      if (t < NT) strenb[buf^1][t] = sp;
    }
    __syncthreads();
  }
  // tail: selection of final round (all epilogues complete at last barrier)
  {
    const int lbuf = (ROUNDS-1) & 1;
    int nbl = n0 + (ROUNDS-1)*NT;
    select16(&simsb[lbuf][row*33 + c0], nbl + c0, CAP - (nbl + c0), tv, ti, minv, mins);
  }
  // merge the two half-row lists -> block top-16 per row (same set as before)
  {
    float* mv_s = &simsb[0][0];
    int*   mi_s = (int*)&simsb[1][0];
    if (t >= 256){  // publish half-1 lists (disjoint from any remaining reads)
      #pragma unroll
      for (int q = 0; q < TOPB; ++q){
        mv_s[row*33 + 16 + q] = tv[q];
        mi_s[row*33 + 16 + q] = ti[q];
      }
    }
    __syncthreads();
    if (t < 256){
      #pragma unroll
      for (int q = 0; q < TOPB; ++q){
        float v = mv_s[t*33 + 16 + q];
        int  gi = mi_s[t*33 + 16 + q];
        if (v > minv) list_insert(tv, ti, minv, mins, v, gi);
      }
      int base = t*(G1*TOPB) + blockIdx.x*TOPB;
      #pragma unroll
      for (int q = 0; q < TOPB; ++q){
        cand_val[base+q] = tv[q];
        cand_idx[base+q] = ti[q];
      }
    }
  }
}

// ---------------- Phase 2: merge 4096 candidates/row -> fp64 rescore 32 -> exact top-10 ----------------
__global__ void k_merge(const float* __restrict__ content,
                        const float* __restrict__ holo,
                        const float* __restrict__ stren,
                        const float* __restrict__ cand_val,
                        const int* __restrict__ cand_idx,
                        int* __restrict__ top_idx)
{
  const int row  = blockIdx.x;
  const int t    = threadIdx.x;   // 256 threads
  const int lane = t & 63;
  const int w    = t >> 6;

  float cv[16]; int ci[16];
  {
    int base = row*(G1*TOPB);
    #pragma unroll
    for (int i = 0; i < 16; ++i){
      int c = i*256 + t;
      cv[i] = cand_val[base + c];
      ci[i] = cand_idx[base + c];
    }
  }
  __shared__ float  lv[4];
  __shared__ int    li[4];
  __shared__ int    sel[MSEL];
  __shared__ double ex[MSEL];
  __shared__ float  cont[D];

  for (int s = 0; s < MSEL; ++s){
    float bv = -INFINITY; int bi = 0x7FFFFFFF;
    #pragma unroll
    for (int i = 0; i < 16; ++i){
      if (cv[i] > bv || (cv[i] == bv && ci[i] < bi)){ bv = cv[i]; bi = ci[i]; }
    }
    #pragma unroll
    for (int off = 1; off < 64; off <<= 1){
      float ov = __shfl_xor(bv, off);
      int   oi = __shfl_xor(bi, off);
      if (ov > bv || (ov == bv && oi < bi)){ bv = ov; bi = oi; }
    }
    if (lane == 0){ lv[w] = bv; li[w] = bi; }
    __syncthreads();
    float wv = lv[0]; int wi = li[0];
    #pragma unroll
    for (int q = 1; q < 4; ++q){
      float ov = lv[q]; int oi = li[q];
      if (ov > wv || (ov == wv && oi < wi)){ wv = ov; wi = oi; }
    }
    if (t == 0) sel[s] = wi;
    #pragma unroll
    for (int i = 0; i < 16; ++i){ if (ci[i] == wi) cv[i] = -INFINITY; }
    __syncthreads();
  }
  if (t < 64) ((float4*)cont)[t] = ((const float4*)content)[row*64 + t];
  __syncthreads();

  // fp64 rescore: wave w -> candidates w*8 .. w*8+7
  const float4* hf4 = (const float4*)holo;
  float4 c4 = ((const float4*)cont)[lane];
  for (int q = 0; q < 8; ++q){
    int s   = w*8 + q;
    int idx = sel[s];
    float4 h4 = hf4[idx*64 + lane];
    double a = (double)h4.x*c4.x + (double)h4.y*c4.y + (double)h4.z*c4.z + (double)h4.w*c4.w;
    #pragma unroll
    for (int off = 1; off < 64; off <<= 1) a += __shfl_xor(a, off);
    if (lane == 0) ex[s] = a * (double)stren[idx];
  }
  __syncthreads();
  if (t == 0){
    unsigned used = 0;
    for (int r = 0; r < TOPK; ++r){
      int best = -1;
      for (int c = 0; c < MSEL; ++c){
        if (used & (1u << c)) continue;
        if (best < 0 || ex[c] > ex[best] || (ex[c] == ex[best] && sel[c] < sel[best])) best = c;
      }
      used |= (1u << best);
      top_idx[row*16 + r] = sel[best];
    }
  }
}

// ---------------- Phase 3: fp32 q/k/v + attention + out-proj ----------------
__global__ __launch_bounds__(512) void k_attn(
    const float* __restrict__ content, const float* __restrict__ holo,
    const float* __restrict__ inw, const float* __restrict__ inb,
    const float* __restrict__ outw, const float* __restrict__ outb,
    const int* __restrict__ top_idx, float* __restrict__ out)
{
  const int b = blockIdx.x;
  const int t = threadIdx.x;
  __shared__ float cont[D];
  __shared__ float mem_s[TOPK*D];
  __shared__ float q_s[D];
  __shared__ float k_s[TOPK*D];
  __shared__ float v_s[TOPK*D];
  __shared__ float sc[H*TOPK];
  __shared__ float at[H*TOPK];
  __shared__ float ctx[D];

  if (t < 64) ((float4*)cont)[t] = ((const float4*)content)[b*64 + t];
  for (int i = t; i < TOPK*D; i += 512){
    int j = i >> 8; int d = i & 255;
    mem_s[i] = holo[(size_t)top_idx[b*16 + j]*D + d];
  }
  __syncthreads();

  const float4* wf4 = (const float4*)inw;
  if (t < 256){ // q projection
    float a = 0.f;
    const float4* c4p = (const float4*)cont;
    #pragma unroll 8
    for (int dc = 0; dc < 64; ++dc){
      float4 wv = wf4[t*64 + dc];
      float4 cc = c4p[dc];
      a += wv.x*cc.x + wv.y*cc.y + wv.z*cc.z + wv.w*cc.w;
    }
    q_s[t] = a + inb[t];
  }
  { // k (threads 0..255) and v (threads 256..511), 10 accumulators each
    int i    = (t < 256) ? t : (t - 256);
    int wrow = (t < 256) ? (256 + i) : (512 + i);
    float a[10];
    #pragma unroll
    for (int j = 0; j < 10; ++j) a[j] = 0.f;
    const float4* m4 = (const float4*)mem_s;
    for (int dc = 0; dc < 64; ++dc){
      float4 wv = wf4[wrow*64 + dc];
      #pragma unroll
      for (int j = 0; j < 10; ++j){
        float4 mm = m4[j*64 + dc];
        a[j] += wv.x*mm.x + wv.y*mm.y + wv.z*mm.z + wv.w*mm.w;
      }
    }
    float bias = inb[wrow];
    if (t < 256){
      #pragma unroll
      for (int j = 0; j < 10; ++j) k_s[j*256 + i] = a[j] + bias;
    } else {
      #pragma unroll
      for (int j = 0; j < 10; ++j) v_s[j*256 + i] = a[j] + bias;
    }
  }
  __syncthreads();
  if (t < H*TOPK){
    int h = t / TOPK, j = t % TOPK;
    float a = 0.f;
    #pragma unroll
    for (int d = 0; d < HD; ++d) a += q_s[h*HD + d] * k_s[j*256 + h*HD + d];
    sc[t] = a * 0.17677669529663687f;   // 1/sqrt(32)
  }
  __syncthreads();
  if (t < H){
    float m = -INFINITY;
    #pragma unroll
    for (int j = 0; j < 10; ++j) m = fmaxf(m, sc[t*10 + j]);
    float e[10]; float su = 0.f;
    #pragma unroll
    for (int j = 0; j < 10; ++j){ e[j] = expf(sc[t*10 + j] - m); su += e[j]; }
    float inv = 1.f / su;
    #pragma unroll
    for (int j = 0; j < 10; ++j) at[t*10 + j] = e[j]*inv;
  }
  __syncthreads();
  if (t < TOPK){ // attn_weights = mean over heads
    float a = 0.f;
    #pragma unroll
    for (int h = 0; h < H; ++h) a += at[h*10 + t];
    out[BATCH*D + b*TOPK + t] = a * 0.125f;
  }
  if (t < 256){ // ctx
    int h = t >> 5;
    float a = 0.f;
    #pragma unroll
    for (int j = 0; j < 10; ++j) a += at[h*10 + j] * v_s[j*256 + t];
    ctx[t] = a;
  }
  __syncthreads();
  if (t < 256){ // out projection
    const float4* of4 = (const float4*)outw;
    const float4* c4p = (const float4*)ctx;
    float a = 0.f;
    #pragma unroll 8
    for (int dc = 0; dc < 64; ++dc){
      float4 wv = of4[t*64 + dc];
      float4 cc = c4p[dc];
      a += wv.x*cc.x + wv.y*cc.y + wv.z*cc.z + wv.w*cc.w;
    }
    out[b*D + t] = a + outb[t];
  }
}

extern "C" void kernel_launch(void* const* d_in, const int* in_sizes, int n_in,
                              void* d_out, int out_size, void* d_ws, size_t ws_size,
                              hipStream_t stream) {
  const float* content = (const float*)d_in[0];
  const float* holo    = (const float*)d_in[1];
  const float* stren   = (const float*)d_in[2];
  const float* inw     = (const float*)d_in[3];
  const float* inb     = (const float*)d_in[4];
  const float* outw    = (const float*)d_in[5];
  const float* outb    = (const float*)d_in[6];
  float* out = (float*)d_out;

  float* cand_val = (float*)d_ws;                         // BATCH*G1*TOPB floats (4 MB)
  int*   cand_idx = (int*)(cand_val + BATCH*G1*TOPB);     // 4 MB
  int*   top_idx  = (int*)(cand_idx + BATCH*G1*TOPB);     // BATCH*16 ints

  hipLaunchKernelGGL(k_score, dim3(G1), dim3(T1), 0, stream,
                     content, holo, stren, cand_val, cand_idx);
  hipLaunchKernelGGL(k_merge, dim3(BATCH), dim3(256), 0, stream,
                     content, holo, stren, cand_val, cand_idx, top_idx);
  hipLaunchKernelGGL(k_attn, dim3(BATCH), dim3(512), 0, stream,
                     content, holo, inw, inb, outw, outb, top_idx, out);
}

// Round 9
// 881.409 us; speedup vs baseline: 1.1968x; 1.0091x over previous
//
#include <hip/hip_runtime.h>
#include <hip/hip_bf16.h>
#include <math.h>

#define D      256
#define H      8
#define HD     32
#define TOPK   10
#define CAP    500000
#define BATCH  256

#define G1     256            // phase-1 blocks (1 per CU)
#define T1     512            // phase-1 threads (8 waves)
#define NT     32             // hologram rows per round
#define ROUNDS 62
#define CHUNK  (NT*ROUNDS)    // 1984 rows per block
#define TOPB   16             // per-block per-row candidates (also per-half-list size)
#define MSEL   32             // exactly-rescored candidates per row

typedef float  f32x16 __attribute__((ext_vector_type(16)));
typedef __bf16 bf16x8 __attribute__((ext_vector_type(8)));

union FragCvt { uint4 u; bf16x8 v; };

__device__ __forceinline__ unsigned bfpair(float lo, float hi){
  unsigned a = __builtin_bit_cast(unsigned, lo);
  unsigned b = __builtin_bit_cast(unsigned, hi);
  a += 0x7FFFu + ((a >> 16) & 1u);   // RNE to bf16
  b += 0x7FFFu + ((b >> 16) & 1u);
  return (a >> 16) | (b & 0xFFFF0000u);
}
__device__ __forceinline__ uint4 pack8(float4 p0, float4 p1){
  uint4 u;
  u.x = bfpair(p0.x, p0.y); u.y = bfpair(p0.z, p0.w);
  u.z = bfpair(p1.x, p1.y); u.w = bfpair(p1.z, p1.w);
  return u;
}

// register-resident top-16 list: replace current-min slot, rescan min (all static idx)
__device__ __forceinline__ void list_insert(float (&tv)[TOPB], int (&ti)[TOPB],
                                            float &minv, int &mins, float v, int gi){
  #pragma unroll
  for (int q = 0; q < TOPB; ++q){ if (q == mins){ tv[q] = v; ti[q] = gi; } }
  float mv = tv[0]; int ms = 0;
  #pragma unroll
  for (int q = 1; q < TOPB; ++q){
    float x = tv[q];
    if (x < mv){ mv = x; ms = q; }
  }
  minv = mv; mins = ms;
}

// scan 16 sims values (constant trip, pipelined ds_reads), batched rare inserts
__device__ __forceinline__ void select16(const float* __restrict__ srow, int gbase, int lim,
                                         float (&tv)[TOPB], int (&ti)[TOPB],
                                         float &minv, int &mins){
  float sv[16];
  #pragma unroll
  for (int j = 0; j < 16; ++j) sv[j] = srow[j];
  unsigned pend = 0u;
  #pragma unroll
  for (int j = 0; j < 16; ++j) pend |= (sv[j] > minv) ? (1u << j) : 0u;
  unsigned limmask = (lim >= 16) ? 0xFFFFu : ((lim <= 0) ? 0u : ((1u << lim) - 1u));
  pend &= limmask;
  while (__any(pend != 0u)){
    if (pend){
      int j = __builtin_ctz(pend);
      pend &= pend - 1u;
      float v = -INFINITY;
      #pragma unroll
      for (int q = 0; q < 16; ++q) v = (q == j) ? sv[q] : v;   // static-index extract
      if (v > minv) list_insert(tv, ti, minv, mins, v, gbase + j);
    }
  }
}

// ---------------- Phase 1: streamed bf16-MFMA sims + per-block top-16 ----------------
__global__ __launch_bounds__(T1) void k_score(
    const float* __restrict__ content, const float* __restrict__ holo,
    const float* __restrict__ stren, float* __restrict__ cand_val,
    int* __restrict__ cand_idx)
{
  // B staged as 16-B frag chunks: chunk (n, kc) at [n*32 + (kc ^ n)]
  // 5-bit XOR swizzle: MFMA reads (32 lanes, fixed kc, varying n=ml) hit 32 DISTINCT
  // 16B slots -> conflict-free; staging writes (srow spans 4 rows/wave, kc0 even)
  // alternate even/odd slot sets by srow parity -> 2 lanes/slot = free (m136).
  // (old 3-bit xor (kc ^ (n&7)) left reads 4-way-conflicted: 1.02e7 SQ_LDS_BANK_CONFLICT)
  __shared__ uint4 Bb[2][NT*32];          // 2 x 16 KB
  __shared__ float simsb[2][BATCH*33];    // 2 x 33.8 KB, double-buffered (33 pad: conflict-free)
  __shared__ float strenb[2][NT];         // strengths tile, double-buffered

  const int t    = threadIdx.x;
  const int lane = t & 63;
  const int w    = t >> 6;       // wave 0..7 -> m-tile rows [32w,32w+32)
  const int half = lane >> 5;
  const int ml   = lane & 31;

  const int row = t & 255;        // selection: 2 threads per row
  const int c0  = (t >> 8) * 16;  // column half [c0, c0+16) of each round

  // A fragments (content rows) in registers, bf16, all K=256 (16 ksteps)
  bf16x8 afrag[16];
  {
    const float4* cf4 = (const float4*)content;
    int base = (w*32 + ml)*64 + half*2;   // float4 units
    #pragma unroll
    for (int ks = 0; ks < 16; ++ks){
      float4 p0 = cf4[base + ks*4 + 0];
      float4 p1 = cf4[base + ks*4 + 1];
      FragCvt fc; fc.u = pack8(p0, p1);
      afrag[ks] = fc.v;
    }
  }

  // per-thread top-16 (of this thread's half-row stream) in registers
  float tv[TOPB]; int ti[TOPB];
  #pragma unroll
  for (int q = 0; q < TOPB; ++q){ tv[q] = -INFINITY; ti[q] = 0; }
  float minv = -INFINITY; int mins = 0;

  const int n0 = blockIdx.x * CHUNK;

  // staging map: thread -> (row srow, 16-float chunk scol)
  const int srow = t >> 4;
  const int scol = t & 15;
  const float4* hf4 = (const float4*)holo;

  float4 st0, st1, st2, st3;
  { // prologue: round 0
    int g  = n0 + srow;
    int gc = (g < CAP) ? g : (CAP-1);
    int gb = gc*64 + scol*4;
    st0 = hf4[gb+0]; st1 = hf4[gb+1]; st2 = hf4[gb+2]; st3 = hf4[gb+3];
    int kc0 = scol*2;
    Bb[0][srow*32 + ((kc0  ) ^ srow)] = pack8(st0, st1);
    Bb[0][srow*32 + ((kc0+1) ^ srow)] = pack8(st2, st3);
    if (t < NT){
      int s0 = n0 + t;
      strenb[0][t] = stren[(s0 < CAP) ? s0 : (CAP-1)];
    }
  }
  __syncthreads();

  for (int r = 0; r < ROUNDS; ++r){
    const int buf = r & 1;
    float sp;
    { // prefetch round r+1 into registers (clamped)
      int g  = n0 + (r+1)*NT + srow;
      int gc = (g < CAP) ? g : (CAP-1);
      int gb = gc*64 + scol*4;
      st0 = hf4[gb+0]; st1 = hf4[gb+1]; st2 = hf4[gb+2]; st3 = hf4[gb+3];
      if (t < NT){
        int s1 = n0 + (r+1)*NT + t;
        sp = stren[(s1 < CAP) ? s1 : (CAP-1)];
      }
    }
    // MFMA over K=256
    f32x16 acc = {0.f,0.f,0.f,0.f,0.f,0.f,0.f,0.f,0.f,0.f,0.f,0.f,0.f,0.f,0.f,0.f};
    const int bbase = ml*32;
    #pragma unroll
    for (int ks = 0; ks < 16; ++ks){
      FragCvt fb; fb.u = Bb[buf][bbase + ((ks*2 + half) ^ ml)];
      acc = __builtin_amdgcn_mfma_f32_32x32x16_bf16(afrag[ks], fb.v, acc, 0, 0, 0);
    }
    // epilogue: sims*stren -> LDS[buf] (C layout: col=lane&31, row=(reg&3)+8*(reg>>2)+4*half)
    {
      float stren_ls = strenb[buf][ml];
      #pragma unroll
      for (int reg = 0; reg < 16; ++reg){
        int rrow = (reg & 3) + 8*(reg >> 2) + 4*half;
        simsb[buf][(w*32 + rrow)*33 + ml] = acc[reg] * stren_ls;
      }
    }
    // selection of round r-1 from the other sims buffer (overlaps MFMA/loads; no extra barrier)
    if (r > 0){
      int nbp = n0 + (r-1)*NT;
      select16(&simsb[buf^1][row*33 + c0], nbp + c0, CAP - (nbp + c0), tv, ti, minv, mins);
    }
    // stage r+1 into other buffer
    {
      int kc0 = scol*2;
      Bb[buf^1][srow*32 + ((kc0  ) ^ srow)] = pack8(st0, st1);
      Bb[buf^1][srow*32 + ((kc0+1) ^ srow)] = pack8(st2, st3);
      if (t < NT) strenb[buf^1][t] = sp;
    }
    __syncthreads();
  }
  // tail: selection of final round (all epilogues complete at last barrier)
  {
    const int lbuf = (ROUNDS-1) & 1;
    int nbl = n0 + (ROUNDS-1)*NT;
    select16(&simsb[lbuf][row*33 + c0], nbl + c0, CAP - (nbl + c0), tv, ti, minv, mins);
  }
  // merge the two half-row lists -> block top-16 per row (same set as before)
  {
    float* mv_s = &simsb[0][0];
    int*   mi_s = (int*)&simsb[1][0];
    if (t >= 256){  // publish half-1 lists (disjoint from any remaining reads)
      #pragma unroll
      for (int q = 0; q < TOPB; ++q){
        mv_s[row*33 + 16 + q] = tv[q];
        mi_s[row*33 + 16 + q] = ti[q];
      }
    }
    __syncthreads();
    if (t < 256){
      #pragma unroll
      for (int q = 0; q < TOPB; ++q){
        float v = mv_s[t*33 + 16 + q];
        int  gi = mi_s[t*33 + 16 + q];
        if (v > minv) list_insert(tv, ti, minv, mins, v, gi);
      }
      int base = t*(G1*TOPB) + blockIdx.x*TOPB;
      #pragma unroll
      for (int q = 0; q < TOPB; ++q){
        cand_val[base+q] = tv[q];
        cand_idx[base+q] = ti[q];
      }
    }
  }
}

// ---------------- Phase 2: merge 4096 candidates/row -> fp64 rescore 32 -> exact top-10 ----------------
__global__ void k_merge(const float* __restrict__ content,
                        const float* __restrict__ holo,
                        const float* __restrict__ stren,
                        const float* __restrict__ cand_val,
                        const int* __restrict__ cand_idx,
                        int* __restrict__ top_idx)
{
  const int row  = blockIdx.x;
  const int t    = threadIdx.x;   // 256 threads
  const int lane = t & 63;
  const int w    = t >> 6;

  float cv[16]; int ci[16];
  {
    int base = row*(G1*TOPB);
    #pragma unroll
    for (int i = 0; i < 16; ++i){
      int c = i*256 + t;
      cv[i] = cand_val[base + c];
      ci[i] = cand_idx[base + c];
    }
  }
  __shared__ float  lv[4];
  __shared__ int    li[4];
  __shared__ int    sel[MSEL];
  __shared__ double ex[MSEL];
  __shared__ float  cont[D];

  for (int s = 0; s < MSEL; ++s){
    float bv = -INFINITY; int bi = 0x7FFFFFFF;
    #pragma unroll
    for (int i = 0; i < 16; ++i){
      if (cv[i] > bv || (cv[i] == bv && ci[i] < bi)){ bv = cv[i]; bi = ci[i]; }
    }
    #pragma unroll
    for (int off = 1; off < 64; off <<= 1){
      float ov = __shfl_xor(bv, off);
      int   oi = __shfl_xor(bi, off);
      if (ov > bv || (ov == bv && oi < bi)){ bv = ov; bi = oi; }
    }
    if (lane == 0){ lv[w] = bv; li[w] = bi; }
    __syncthreads();
    float wv = lv[0]; int wi = li[0];
    #pragma unroll
    for (int q = 1; q < 4; ++q){
      float ov = lv[q]; int oi = li[q];
      if (ov > wv || (ov == wv && oi < wi)){ wv = ov; wi = oi; }
    }
    if (t == 0) sel[s] = wi;
    #pragma unroll
    for (int i = 0; i < 16; ++i){ if (ci[i] == wi) cv[i] = -INFINITY; }
    __syncthreads();
  }
  if (t < 64) ((float4*)cont)[t] = ((const float4*)content)[row*64 + t];
  __syncthreads();

  // fp64 rescore: wave w -> candidates w*8 .. w*8+7
  const float4* hf4 = (const float4*)holo;
  float4 c4 = ((const float4*)cont)[lane];
  for (int q = 0; q < 8; ++q){
    int s   = w*8 + q;
    int idx = sel[s];
    float4 h4 = hf4[idx*64 + lane];
    double a = (double)h4.x*c4.x + (double)h4.y*c4.y + (double)h4.z*c4.z + (double)h4.w*c4.w;
    #pragma unroll
    for (int off = 1; off < 64; off <<= 1) a += __shfl_xor(a, off);
    if (lane == 0) ex[s] = a * (double)stren[idx];
  }
  __syncthreads();
  if (t == 0){
    unsigned used = 0;
    for (int r = 0; r < TOPK; ++r){
      int best = -1;
      for (int c = 0; c < MSEL; ++c){
        if (used & (1u << c)) continue;
        if (best < 0 || ex[c] > ex[best] || (ex[c] == ex[best] && sel[c] < sel[best])) best = c;
      }
      used |= (1u << best);
      top_idx[row*16 + r] = sel[best];
    }
  }
}

// ---------------- Phase 3: fp32 q/k/v + attention + out-proj ----------------
__global__ __launch_bounds__(512) void k_attn(
    const float* __restrict__ content, const float* __restrict__ holo,
    const float* __restrict__ inw, const float* __restrict__ inb,
    const float* __restrict__ outw, const float* __restrict__ outb,
    const int* __restrict__ top_idx, float* __restrict__ out)
{
  const int b = blockIdx.x;
  const int t = threadIdx.x;
  __shared__ float cont[D];
  __shared__ float mem_s[TOPK*D];
  __shared__ float q_s[D];
  __shared__ float k_s[TOPK*D];
  __shared__ float v_s[TOPK*D];
  __shared__ float sc[H*TOPK];
  __shared__ float at[H*TOPK];
  __shared__ float ctx[D];

  if (t < 64) ((float4*)cont)[t] = ((const float4*)content)[b*64 + t];
  for (int i = t; i < TOPK*D; i += 512){
    int j = i >> 8; int d = i & 255;
    mem_s[i] = holo[(size_t)top_idx[b*16 + j]*D + d];
  }
  __syncthreads();

  const float4* wf4 = (const float4*)inw;
  if (t < 256){ // q projection
    float a = 0.f;
    const float4* c4p = (const float4*)cont;
    #pragma unroll 8
    for (int dc = 0; dc < 64; ++dc){
      float4 wv = wf4[t*64 + dc];
      float4 cc = c4p[dc];
      a += wv.x*cc.x + wv.y*cc.y + wv.z*cc.z + wv.w*cc.w;
    }
    q_s[t] = a + inb[t];
  }
  { // k (threads 0..255) and v (threads 256..511), 10 accumulators each
    int i    = (t < 256) ? t : (t - 256);
    int wrow = (t < 256) ? (256 + i) : (512 + i);
    float a[10];
    #pragma unroll
    for (int j = 0; j < 10; ++j) a[j] = 0.f;
    const float4* m4 = (const float4*)mem_s;
    for (int dc = 0; dc < 64; ++dc){
      float4 wv = wf4[wrow*64 + dc];
      #pragma unroll
      for (int j = 0; j < 10; ++j){
        float4 mm = m4[j*64 + dc];
        a[j] += wv.x*mm.x + wv.y*mm.y + wv.z*mm.z + wv.w*mm.w;
      }
    }
    float bias = inb[wrow];
    if (t < 256){
      #pragma unroll
      for (int j = 0; j < 10; ++j) k_s[j*256 + i] = a[j] + bias;
    } else {
      #pragma unroll
      for (int j = 0; j < 10; ++j) v_s[j*256 + i] = a[j] + bias;
    }
  }
  __syncthreads();
  if (t < H*TOPK){
    int h = t / TOPK, j = t % TOPK;
    float a = 0.f;
    #pragma unroll
    for (int d = 0; d < HD; ++d) a += q_s[h*HD + d] * k_s[j*256 + h*HD + d];
    sc[t] = a * 0.17677669529663687f;   // 1/sqrt(32)
  }
  __syncthreads();
  if (t < H){
    float m = -INFINITY;
    #pragma unroll
    for (int j = 0; j < 10; ++j) m = fmaxf(m, sc[t*10 + j]);
    float e[10]; float su = 0.f;
    #pragma unroll
    for (int j = 0; j < 10; ++j){ e[j] = expf(sc[t*10 + j] - m); su += e[j]; }
    float inv = 1.f / su;
    #pragma unroll
    for (int j = 0; j < 10; ++j) at[t*10 + j] = e[j]*inv;
  }
  __syncthreads();
  if (t < TOPK){ // attn_weights = mean over heads
    float a = 0.f;
    #pragma unroll
    for (int h = 0; h < H; ++h) a += at[h*10 + t];
    out[BATCH*D + b*TOPK + t] = a * 0.125f;
  }
  if (t < 256){ // ctx
    int h = t >> 5;
    float a = 0.f;
    #pragma unroll
    for (int j = 0; j < 10; ++j) a += at[h*10 + j] * v_s[j*256 + t];
    ctx[t] = a;
  }
  __syncthreads();
  if (t < 256){ // out projection
    const float4* of4 = (const float4*)outw;
    const float4* c4p = (const float4*)ctx;
    float a = 0.f;
    #pragma unroll 8
    for (int dc = 0; dc < 64; ++dc){
      float4 wv = of4[t*64 + dc];
      float4 cc = c4p[dc];
      a += wv.x*cc.x + wv.y*cc.y + wv.z*cc.z + wv.w*cc.w;
    }
    out[b*D + t] = a + outb[t];
  }
}

extern "C" void kernel_launch(void* const* d_in, const int* in_sizes, int n_in,
                              void* d_out, int out_size, void* d_ws, size_t ws_size,
                              hipStream_t stream) {
  const float* content = (const float*)d_in[0];
  const float* holo    = (const float*)d_in[1];
  const float* stren   = (const float*)d_in[2];
  const float* inw     = (const float*)d_in[3];
  const float* inb     = (const float*)d_in[4];
  const float* outw    = (const float*)d_in[5];
  const float* outb    = (const float*)d_in[6];
  float* out = (float*)d_out;

  float* cand_val = (float*)d_ws;                         // BATCH*G1*TOPB floats (4 MB)
  int*   cand_idx = (int*)(cand_val + BATCH*G1*TOPB);     // 4 MB
  int*   top_idx  = (int*)(cand_idx + BATCH*G1*TOPB);     // BATCH*16 ints

  hipLaunchKernelGGL(k_score, dim3(G1), dim3(T1), 0, stream,
                     content, holo, stren, cand_val, cand_idx);
  hipLaunchKernelGGL(k_merge, dim3(BATCH), dim3(256), 0, stream,
                     content, holo, stren, cand_val, cand_idx, top_idx);
  hipLaunchKernelGGL(k_attn, dim3(BATCH), dim3(512), 0, stream,
                     content, holo, inw, inb, outw, outb, top_idx, out);
}